// Round 1
// baseline (332.684 us; speedup 1.0000x reference)
//
#include <hip/hip_runtime.h>

// Problem constants (from reference): H=256, N=100000, B=8, S=128 -> T=1024
#define T_ROWS 1024
#define H_DIM  256
#define N_COLS 100000
#define BN     64
#define QF     127.0f

typedef __attribute__((ext_vector_type(4))) float f32x4;
typedef __attribute__((ext_vector_type(8))) short short8;   // 8 bf16 = 4 VGPRs (MFMA A/B frag)
typedef __attribute__((ext_vector_type(4))) short short4v;  // 4 bf16 = 8B

__device__ __forceinline__ float wave_absmax(float v) {
#pragma unroll
    for (int off = 32; off > 0; off >>= 1)
        v = fmaxf(v, __shfl_xor(v, off, 64));
    return v;
}

// Exact f32 -> bf16 for integer-valued floats |q| <= 127 (7 significant bits
// fit bf16's 8-bit significand): plain truncation of the top 16 bits is exact.
__device__ __forceinline__ short f32_to_bf16_exact(float f) {
    unsigned u = __builtin_bit_cast(unsigned, f);
    return (short)(u >> 16);
}

// ---------------- Kernel 1: per-row quantize X -> integer-valued bf16 + absmax
__global__ __launch_bounds__(256) void quant_x(const float* __restrict__ X,
                                               short* __restrict__ x8,
                                               float* __restrict__ sx) {
    const int w = threadIdx.x >> 6, l = threadIdx.x & 63;
    const int row = blockIdx.x * 4 + w;            // wave per row, 4 rows/block
    const float4 v = ((const float4*)X)[row * 64 + l];   // coalesced 16B/lane
    float amax = fmaxf(fmaxf(fabsf(v.x), fabsf(v.y)), fmaxf(fabsf(v.z), fabsf(v.w)));
    amax = wave_absmax(amax);
    const float scale = (amax == 0.f) ? 1.f : amax;
    const float qs = QF / scale;                   // matches ref: x * (127/scale)
    short4v q;
    q.x = f32_to_bf16_exact(rintf(v.x * qs));      // rintf == jnp.rint (RNE)
    q.y = f32_to_bf16_exact(rintf(v.y * qs));
    q.z = f32_to_bf16_exact(rintf(v.z * qs));
    q.w = f32_to_bf16_exact(rintf(v.w * qs));
    *(short4v*)(x8 + row * H_DIM + l * 4) = q;     // plain row-major [1024][256]
    if (l == 0) sx[row] = amax;
}

// ---------------- Kernel 2: fused W-quantize + bf16-MFMA int GEMM + dequant
// Block: 64 W-rows (n-tile). W fp32 read exactly once. LDS holds swizzled
// bf16 W tile; B-frags hoisted to regs (t-invariant). Loop all 16 T-tiles.
__global__ __launch_bounds__(256, 3) void gemm_main(const float* __restrict__ W,
                                                    const float* __restrict__ bias,
                                                    const short* __restrict__ x8,
                                                    const float* __restrict__ sx,
                                                    float* __restrict__ out) {
    __shared__ short wlds[BN * H_DIM];   // 32KB bf16, XOR-swizzled rows
    __shared__ float sw_lds[BN];

    const int tid = threadIdx.x;
    const int w = tid >> 6, l = tid & 63;
    const int n0 = blockIdx.x * BN;

    // --- quantize 64 W rows: one wave per row, 16 rows per wave
    const float4* W4 = (const float4*)W;
#pragma unroll 4
    for (int r = 0; r < 16; ++r) {
        const int row = r * 4 + w;
        const int n = n0 + row;
        float4 v;
        if (n < N_COLS) v = W4[(size_t)n * 64 + l];
        else { v.x = 0.f; v.y = 0.f; v.z = 0.f; v.w = 0.f; }
        float amax = fmaxf(fmaxf(fabsf(v.x), fabsf(v.y)), fmaxf(fabsf(v.z), fabsf(v.w)));
        amax = wave_absmax(amax);
        const float scale = (amax == 0.f) ? 1.f : amax;
        const float qs = QF / scale;
        short4v q;
        q.x = f32_to_bf16_exact(rintf(v.x * qs));
        q.y = f32_to_bf16_exact(rintf(v.y * qs));
        q.z = f32_to_bf16_exact(rintf(v.z * qs));
        q.w = f32_to_bf16_exact(rintf(v.w * qs));
        // swizzle: short-index XOR (row&7)<<3  (== byte XOR (row&7)<<4)
        const int sidx = row * H_DIM + ((l * 4) ^ ((row & 7) << 3));
        *(short4v*)(wlds + sidx) = q;
        if (l == 0) sw_lds[row] = amax;
    }
    __syncthreads();

    const int wm = w >> 1, wn = w & 1;       // 2m x 2n wave grid
    const int lg = l >> 4, lm = l & 15;

    // per-lane column constants: absmax_w, bias
    float swv[2], bv[2];
#pragma unroll
    for (int nr = 0; nr < 2; ++nr) {
        const int ncol = wn * 32 + nr * 16 + lm;
        swv[nr] = sw_lds[ncol];
        const int n = n0 + ncol;
        bv[nr] = (n < N_COLS) ? bias[n] : 0.f;
    }

    // B fragments (t-invariant): B[k][n]=W[n][k]; lane: n=lm, k=kk*32+8*lg+j
    short8 bfr[2][8];
#pragma unroll
    for (int nr = 0; nr < 2; ++nr) {
        const int row = wn * 32 + nr * 16 + lm;
#pragma unroll
        for (int kk = 0; kk < 8; ++kk) {
            const int sidx = row * H_DIM + ((kk * 32 + 8 * lg) ^ ((row & 7) << 3));
            bfr[nr][kk] = *(const short8*)(wlds + sidx);
        }
    }

    const float invqq = 1.0f / (QF * QF);
    const f32x4 zero4 = {0.f, 0.f, 0.f, 0.f};

    for (int tt = 0; tt < 16; ++tt) {
        const int t0 = tt * 64;
        f32x4 acc[2][2];
        acc[0][0] = zero4; acc[0][1] = zero4; acc[1][0] = zero4; acc[1][1] = zero4;

        // A frags direct from L2-resident x8 (512KB total; no LDS staging)
        const short* abase0 = x8 + (t0 + wm * 32 + lm) * H_DIM + 8 * lg;
#pragma unroll
        for (int kk = 0; kk < 8; ++kk) {
            const short8 a0 = *(const short8*)(abase0 + kk * 32);
            const short8 a1 = *(const short8*)(abase0 + 16 * H_DIM + kk * 32);
            acc[0][0] = __builtin_amdgcn_mfma_f32_16x16x32_bf16(a0, bfr[0][kk], acc[0][0], 0, 0, 0);
            acc[0][1] = __builtin_amdgcn_mfma_f32_16x16x32_bf16(a0, bfr[1][kk], acc[0][1], 0, 0, 0);
            acc[1][0] = __builtin_amdgcn_mfma_f32_16x16x32_bf16(a1, bfr[0][kk], acc[1][0], 0, 0, 0);
            acc[1][1] = __builtin_amdgcn_mfma_f32_16x16x32_bf16(a1, bfr[1][kk], acc[1][1], 0, 0, 0);
        }

        // epilogue: dequant + bias, coalesced dword stores
        // C/D layout (m89-verified): col = lane&15, row = (lane>>4)*4 + r
#pragma unroll
        for (int mr = 0; mr < 2; ++mr) {
            const int trow = t0 + wm * 32 + mr * 16 + lg * 4;
#pragma unroll
            for (int r = 0; r < 4; ++r) {
                const int t = trow + r;
                const float sxv = sx[t];
#pragma unroll
                for (int nr = 0; nr < 2; ++nr) {
                    const int n = n0 + wn * 32 + nr * 16 + lm;
                    if (n < N_COLS)
                        out[(size_t)t * N_COLS + n] =
                            acc[mr][nr][r] * ((sxv * swv[nr]) * invqq) + bv[nr];
                }
            }
        }
    }
}

extern "C" void kernel_launch(void* const* d_in, const int* in_sizes, int n_in,
                              void* d_out, int out_size, void* d_ws, size_t ws_size,
                              hipStream_t stream) {
    const float* X    = (const float*)d_in[0];   // [8,128,256] f32
    const float* W    = (const float*)d_in[1];   // [100000,256] f32
    const float* bias = (const float*)d_in[2];   // [100000] f32
    float* out = (float*)d_out;                  // [1024,100000] f32

    short* x8 = (short*)d_ws;                                     // 512KB bf16
    float* sx = (float*)((char*)d_ws + (size_t)T_ROWS * H_DIM * 2); // 4KB

    quant_x<<<T_ROWS / 4, 256, 0, stream>>>(X, x8, sx);

    const int grid = (N_COLS + BN - 1) / BN;     // 1563
    gemm_main<<<grid, 256, 0, stream>>>(W, bias, x8, sx, out);
}